// Round 1
// baseline (329.528 us; speedup 1.0000x reference)
//
#include <hip/hip_runtime.h>

// Conv1d via implicit GEMM on MFMA f16.
// out[b,co,t] = bias[co] + sum_{ci,m} w[co,ci,m] * x[b,ci,t-32+m], t in [0,4032)
// (exact rewrite of the reference FFT path; wrap-around only touches zero pad)

typedef _Float16 f16;
typedef _Float16 f16x8 __attribute__((ext_vector_type(8)));
typedef float f32x4 __attribute__((ext_vector_type(4)));

#define NB   16
#define CI   128
#define CO   128
#define LIN  4096
#define KW   129
#define TOUT 4032
#define UPAD 4224                 // xT rows per batch: covers u in [0, 3968+128+128)
#define KCH  516                  // 129 taps * 4 ci-chunks of 32
#define XT_BYTES ((size_t)NB * UPAD * CI * 2)   // 17,301,504

__device__ __forceinline__ void gld16(void* lds, const void* g) {
    __builtin_amdgcn_global_load_lds(
        (const __attribute__((address_space(1))) unsigned int*)g,
        (__attribute__((address_space(3))) unsigned int*)lds,
        16, 0, 0);
}

// ---------------- pre-pass 1: x (f32, [b][ci][l]) -> xT (f16, [b][u][ci], swizzled) ----
// u = l + 32; rows u<32 and u>=4128 are zero. Within each 256B row, 16B chunk c
// is stored at slot c ^ (u&7)  (bank-conflict swizzle, consumed by main kernel).
__global__ __launch_bounds__(256) void xt_prep(const float* __restrict__ x,
                                               f16* __restrict__ xt) {
    __shared__ float tile[128][33];           // [ci][lcol], +1 pad
    const int b  = blockIdx.y;
    const int u0 = blockIdx.x * 32;
    const int l0 = u0 - 32;
    const int tid = threadIdx.x;
    const int col = tid & 31;
    const int cib = tid >> 5;                 // 0..7
#pragma unroll
    for (int r = 0; r < 16; ++r) {
        int ci = cib + r * 8;
        int l  = l0 + col;
        float v = 0.f;
        if (l >= 0 && l < LIN) v = x[((size_t)b * CI + ci) * LIN + l];
        tile[ci][col] = v;
    }
    __syncthreads();
#pragma unroll
    for (int it = 0; it < 2; ++it) {
        int idx  = tid + it * 256;            // 0..511 = 32 rows * 16 chunks
        int ur   = idx >> 4;
        int slot = idx & 15;
        int c    = slot ^ ((u0 + ur) & 7);    // logical chunk stored at this slot
        f16x8 v;
#pragma unroll
        for (int j = 0; j < 8; ++j) v[j] = (f16)tile[c * 8 + j][ur];
        *(f16x8*)(&xt[((size_t)b * UPAD + u0 + ur) * CI + slot * 8]) = v;
    }
}

// ---------------- pre-pass 2: w (f32, [co][ci][m]) -> wT (f16, [kk][co][32ci], swizzled)
// kk = m*4 + cic.  Within each 64B row, 16B chunk c stored at slot c ^ ((co>>1)&3).
__global__ __launch_bounds__(256) void wt_prep(const float* __restrict__ w,
                                               f16* __restrict__ wt) {
    __shared__ float tile[32][132];           // [ci_local][m], padded
    const int cic = blockIdx.x;               // 0..3
    const int co  = blockIdx.y;               // 0..127
    const int ci0 = cic * 32;
    const int tid = threadIdx.x;
    for (int it = 0; it < 17; ++it) {
        int idx = tid + it * 256;
        if (idx < 32 * 129) {
            int i = idx / 129;
            int m = idx - i * 129;
            tile[i][m] = w[(size_t)co * (CI * KW) + (size_t)(ci0 + i) * KW + m];
        }
    }
    __syncthreads();
    const int swz = (co >> 1) & 3;
    for (int it = 0; it < 3; ++it) {
        int idx = tid + it * 256;
        if (idx < 129 * 4) {
            int m = idx >> 2;
            int c = idx & 3;
            int kk = m * 4 + cic;
            int slot = c ^ swz;
            f16x8 v;
#pragma unroll
            for (int j = 0; j < 8; ++j) v[j] = (f16)tile[c * 8 + j][m];
            *(f16x8*)(&wt[((size_t)kk * 128 + co) * 32 + slot * 8]) = v;
        }
    }
}

// ---------------- main kernel: 128co x 128t per block, 4 waves of 64x64 --------------
// LDS: xs = 256 rows x 128B (one ci-half of the x tile, swizzled)     = 32 KB
//      wb = 2 x [128co][64B]                                          = 16 KB
__global__ __launch_bounds__(256, 3) void conv_main(
    const f16* __restrict__ xt, const f16* __restrict__ wt,
    const float* __restrict__ bias, float* __restrict__ out)
{
    extern __shared__ char smem[];
    const int tid  = threadIdx.x;
    const int lane = tid & 63;
    const int wid  = tid >> 6;
    const int l15  = lane & 15;
    const int l4   = lane >> 4;
    const int wco  = (wid >> 1) << 6;     // 0 / 64
    const int wtt  = (wid & 1) << 6;      // 0 / 64

    const int tt = blockIdx.x;            // 0..31 (t-tile)
    const int b  = blockIdx.y;            // 0..15
    const int u0 = tt << 7;

    const char* xbase = (const char*)xt + ((size_t)b * UPAD + u0) * (CI * 2);
    const char* wbase = (const char*)wt;

    // loop-invariant A-fragment offsets: slot = l4 ^ ((co>>1)&3), ct-independent part
    const int aslotx = (l4 ^ ((l15 >> 1) & 3)) << 4;
    int aoff[4];
#pragma unroll
    for (int ct = 0; ct < 4; ++ct)
        aoff[ct] = ((wco + ct * 16 + l15) << 6) + aslotx;

    int brow[4];
#pragma unroll
    for (int st = 0; st < 4; ++st)
        brow[st] = wtt + st * 16 + l15;

    f32x4 acc[4][4];
#pragma unroll
    for (int i = 0; i < 4; ++i)
#pragma unroll
        for (int j = 0; j < 4; ++j)
            acc[i][j] = (f32x4){0.f, 0.f, 0.f, 0.f};

    for (int p = 0; p < 2; ++p) {         // ci-halves: ci in [p*64, p*64+64)
        // stage x half: 256 rows x 128B, linear in LDS, per-lane global addresses
#pragma unroll
        for (int i = 0; i < 8; ++i) {
            int off   = tid * 16 + i * 4096;
            int row   = off >> 7;
            int inrow = off & 127;
            gld16(smem + off, xbase + row * 256 + p * 128 + inrow);
        }
        // stage first W chunk of this phase (kk = 2p) into buf0
        {
            const char* wsrc = wbase + (size_t)(2 * p) * 8192;
            gld16(smem + 32768 + tid * 16, wsrc + tid * 16);
            gld16(smem + 32768 + 4096 + tid * 16, wsrc + 4096 + tid * 16);
        }
        __syncthreads();

#pragma unroll 2
        for (int s = 0; s < 258; ++s) {   // m = s>>1, cic = 2p + (s&1)
            const int bufo = (s & 1) << 13;
            if (s + 1 < 258) {            // prefetch next W chunk (2-phase pattern)
                int sn    = s + 1;
                int chunk = ((sn >> 1) << 2) + 2 * p + (sn & 1);
                const char* wsrc = wbase + (size_t)chunk * 8192;
                int nbufo = 8192 - bufo;
                gld16(smem + 32768 + nbufo + tid * 16, wsrc + tid * 16);
                gld16(smem + 32768 + nbufo + 4096 + tid * 16, wsrc + 4096 + tid * 16);
            }
            const int m  = s >> 1;
            const int cl = ((s & 1) << 2) + l4;     // local logical chunk in [0,8)

            f16x8 af[4], bf[4];
#pragma unroll
            for (int ct = 0; ct < 4; ++ct)
                af[ct] = *(const f16x8*)(smem + 32768 + bufo + aoff[ct]);
#pragma unroll
            for (int st = 0; st < 4; ++st) {
                int row  = brow[st] + m;
                int slot = cl ^ (row & 7);
                bf[st] = *(const f16x8*)(smem + (row << 7) + (slot << 4));
            }
#pragma unroll
            for (int ct = 0; ct < 4; ++ct)
#pragma unroll
                for (int st = 0; st < 4; ++st)
                    acc[ct][st] = __builtin_amdgcn_mfma_f32_16x16x32_f16(
                        af[ct], bf[st], acc[ct][st], 0, 0, 0);
            __syncthreads();
        }
    }

    // epilogue: D[row=co_local][col=t_local]; row=(l>>4)*4+reg, col=l&15
#pragma unroll
    for (int ct = 0; ct < 4; ++ct) {
#pragma unroll
        for (int r = 0; r < 4; ++r) {
            int co = wco + ct * 16 + l4 * 4 + r;
            float bv = bias[co];
            float* orow = out + ((size_t)b * CO + co) * TOUT;
#pragma unroll
            for (int st = 0; st < 4; ++st) {
                int t = u0 + wtt + st * 16 + l15;
                if (t < TOUT) orow[t] = acc[ct][st][r] + bv;
            }
        }
    }
}

extern "C" void kernel_launch(void* const* d_in, const int* in_sizes, int n_in,
                              void* d_out, int out_size, void* d_ws, size_t ws_size,
                              hipStream_t stream) {
    const float* x    = (const float*)d_in[0];
    const float* w    = (const float*)d_in[1];
    const float* bias = (const float*)d_in[2];
    float* out = (float*)d_out;

    f16* xt = (f16*)d_ws;                              // 17,301,504 B
    f16* wt = (f16*)((char*)d_ws + XT_BYTES);          //  4,227,072 B

    xt_prep<<<dim3(UPAD / 32, NB), 256, 0, stream>>>(x, xt);
    wt_prep<<<dim3(4, CO), 256, 0, stream>>>(w, wt);
    conv_main<<<dim3(32, NB), 256, 49152, stream>>>(xt, wt, bias, out);
}